// Round 10
// baseline (19.793 us; speedup 1.0000x reference)
//
#include <hip/hip_runtime.h>

#define RR 300
#define NCLS 37
#define COUT 36
#define NSTRIP 5
#define CAP2 128           // max candidates (2/lane)
#define SCORE_THR_C 0.1f
#define NMS_THR_C 0.4f

__device__ __forceinline__ float readlanef(float x, int sl) {
    return __uint_as_float((unsigned)__builtin_amdgcn_readlane((int)__float_as_uint(x), sl));
}
__device__ __forceinline__ int readlanei(int x, int sl) {
    return __builtin_amdgcn_readlane(x, sl);
}

// One wave per (b,c). All global loads issued upfront (no dependent gathers);
// raw rois/pred staged in LDS; lazy decode of candidates from LDS; serial
// readlane greedy scan; output staged in LDS and written as float4.
__global__ __launch_bounds__(64) void det_wave6_kernel(
    const float* __restrict__ rois,
    const float* __restrict__ pred,
    const float* __restrict__ scr,
    const float* __restrict__ iminfo,
    float* __restrict__ out)
{
#pragma clang fp contract(off)
    const int bid  = blockIdx.x;
    const int lane = threadIdx.x;                  // 0..63
    // XCD swizzle: 1152 = 8 * 144; XCD k owns batches [4k, 4k+4).
    const int bc   = (bid & 7) * 144 + (bid >> 3);
    const int b    = bc / COUT;
    const int c    = bc % COUT;
    const int cls  = c + 1;

    __shared__ __align__(16) float4 Lro[RR];       // raw rois rows (4.8 KB)
    __shared__ __align__(16) float4 Lpp[RR];       // raw pred slices (4.8 KB)
    __shared__ __align__(16) float  csc[CAP2 + 4]; // compact scores + pad
    __shared__ int          cro[CAP2];             // compact orig r
    __shared__ __align__(16) float4 sbx[CAP2];     // sorted boxes
    __shared__ int          sor[CAP2];             // sorted orig r
    __shared__ float        ssc[CAP2];             // sorted scores
    __shared__ __align__(16) float obuf[1500];     // output block (6 KB)

    // ---- phase 1: issue ALL global loads upfront; stage raw rows to LDS ----
    float ss[NSTRIP];
    bool  vv[NSTRIP];
    #pragma unroll
    for (int t = 0; t < NSTRIP; ++t) {
        const int r = lane + 64 * t;
        if (r < RR) {
            const float4 ro = *reinterpret_cast<const float4*>(rois + (size_t)(b * RR + r) * 4);
            const float4 pp = *reinterpret_cast<const float4*>(pred + (size_t)(b * RR + r) * (4 * NCLS) + 4 * cls);
            ss[t] = scr[(size_t)(b * RR + r) * NCLS + cls];
            Lro[r] = ro;
            Lpp[r] = pp;
        } else {
            ss[t] = 0.f;
        }
        vv[t] = (lane + 64 * t < RR) && (ss[t] > SCORE_THR_C);
    }
    // zero output staging block (375 float4) — overlaps with load latency
    float4* ob4 = reinterpret_cast<float4*>(obuf);
    #pragma unroll
    for (int k = 0; k < 6; ++k) {
        const int i = lane + 64 * k;
        if (i < 375) ob4[i] = make_float4(0.f, 0.f, 0.f, 0.f);
    }

    // ---- phase 2: compaction (valid set == prefix of stable argsort(-s)) ----
    const unsigned long long lmask = (1ull << lane) - 1ull;
    int pos[NSTRIP];
    int acc = 0;
    #pragma unroll
    for (int t = 0; t < NSTRIP; ++t) {
        const unsigned long long balt = __ballot(vv[t]);
        pos[t] = acc + __popcll(balt & lmask);
        acc   += __popcll(balt);
    }
    int nv = __builtin_amdgcn_readfirstlane(acc);
    if (nv > CAP2) nv = CAP2;

    #pragma unroll
    for (int t = 0; t < NSTRIP; ++t) {
        if (vv[t] && pos[t] < CAP2) {
            csc[pos[t]] = ss[t];
            cro[pos[t]] = lane + 64 * t;
        }
    }
    if (lane < 4) csc[nv + lane] = -1.0f;          // pad for float4 rank loop

    // ---- phase 3: lazy decode of candidates, gathering raw rows from LDS ----
    const float Hm1 = iminfo[b * 3 + 0] - 1.0f;
    const float Wm1 = iminfo[b * 3 + 1] - 1.0f;
    const float scl = iminfo[2];   // im_info[0, 2] for ALL batches (per reference)

    const bool has2 = (nv > 64);
    const bool a0 = (lane < nv);
    const bool a1 = has2 && (lane + 64 < nv);

    float  s0 = -2.f, s1 = -2.f;
    int    o0 = 0, o1 = 0;
    float4 b0 = make_float4(0.f, 0.f, 0.f, 0.f), b1 = b0;
    if (a0) {
        s0 = csc[lane];
        o0 = cro[lane];
        const float4 ro = Lro[o0];
        const float4 pp = Lpp[o0];
        float w  = ro.z - ro.x + 1.0f;
        float h  = ro.w - ro.y + 1.0f;
        float cx = ro.x + 0.5f * w;
        float cy = ro.y + 0.5f * h;
        float dx = pp.x * 0.1f;
        float dy = pp.y * 0.1f;
        float dw = pp.z * 0.2f;
        float dh = pp.w * 0.2f;
        float pcx = dx * w + cx;
        float pcy = dy * h + cy;
        float pw  = expf(dw) * w;
        float ph  = expf(dh) * h;
        b0.x = fminf(fmaxf(pcx - 0.5f * pw, 0.0f), Wm1) / scl;
        b0.y = fminf(fmaxf(pcy - 0.5f * ph, 0.0f), Hm1) / scl;
        b0.z = fminf(fmaxf(pcx + 0.5f * pw, 0.0f), Wm1) / scl;
        b0.w = fminf(fmaxf(pcy + 0.5f * ph, 0.0f), Hm1) / scl;
    }
    if (a1) {
        s1 = csc[lane + 64];
        o1 = cro[lane + 64];
        const float4 ro = Lro[o1];
        const float4 pp = Lpp[o1];
        float w  = ro.z - ro.x + 1.0f;
        float h  = ro.w - ro.y + 1.0f;
        float cx = ro.x + 0.5f * w;
        float cy = ro.y + 0.5f * h;
        float dx = pp.x * 0.1f;
        float dy = pp.y * 0.1f;
        float dw = pp.z * 0.2f;
        float dh = pp.w * 0.2f;
        float pcx = dx * w + cx;
        float pcy = dy * h + cy;
        float pw  = expf(dw) * w;
        float ph  = expf(dh) * h;
        b1.x = fminf(fmaxf(pcx - 0.5f * pw, 0.0f), Wm1) / scl;
        b1.y = fminf(fmaxf(pcy - 0.5f * ph, 0.0f), Hm1) / scl;
        b1.z = fminf(fmaxf(pcx + 0.5f * pw, 0.0f), Wm1) / scl;
        b1.w = fminf(fmaxf(pcy + 0.5f * ph, 0.0f), Hm1) / scl;
    }

    // ---- phase 4: stable descending rank (float4 LDS reads) ----
    int r0 = 0, r1 = 0;
    const float4* cs4 = reinterpret_cast<const float4*>(&csc[0]);
    const int n4 = (nv + 3) >> 2;
    for (int q4 = 0; q4 < n4; ++q4) {
        const float4 sv = cs4[q4];
        const int qb = q4 * 4;
        r0 += (int)(sv.x > s0) + ((int)(sv.x == s0) & (int)(qb + 0 < lane));
        r0 += (int)(sv.y > s0) + ((int)(sv.y == s0) & (int)(qb + 1 < lane));
        r0 += (int)(sv.z > s0) + ((int)(sv.z == s0) & (int)(qb + 2 < lane));
        r0 += (int)(sv.w > s0) + ((int)(sv.w == s0) & (int)(qb + 3 < lane));
    }
    if (has2) {
        for (int q4 = 0; q4 < n4; ++q4) {
            const float4 sv = cs4[q4];
            const int qb = q4 * 4, me = lane + 64;
            r1 += (int)(sv.x > s1) + ((int)(sv.x == s1) & (int)(qb + 0 < me));
            r1 += (int)(sv.y > s1) + ((int)(sv.y == s1) & (int)(qb + 1 < me));
            r1 += (int)(sv.z > s1) + ((int)(sv.z == s1) & (int)(qb + 2 < me));
            r1 += (int)(sv.w > s1) + ((int)(sv.w == s1) & (int)(qb + 3 < me));
        }
    }

    // ---- phase 5: scatter by rank; readback sorted candidates ----
    if (a0) { sbx[r0] = b0; sor[r0] = o0; ssc[r0] = s0; }
    if (a1) { sbx[r1] = b1; sor[r1] = o1; ssc[r1] = s1; }
    float4 sb0 = make_float4(0.f, 0.f, 0.f, 0.f), sb1 = sb0;
    float  sa0 = 0.f, sa1 = 0.f, sc0 = 0.f, sc1 = 0.f;
    int    so0 = 0, so1 = 0;
    if (a0) { sb0 = sbx[lane];      so0 = sor[lane];      sc0 = ssc[lane];
              sa0 = (sb0.z - sb0.x) * (sb0.w - sb0.y); }
    if (a1) { sb1 = sbx[lane + 64]; so1 = sor[lane + 64]; sc1 = ssc[lane + 64];
              sa1 = (sb1.z - sb1.x) * (sb1.w - sb1.y); }

    // ---- phase 6: greedy scan, pivot broadcast via v_readlane ----
    unsigned long long lv0, lv1, kb0 = 0ull, kb1 = 0ull;
    lv0 = (nv >= 64) ? ~0ull : ((1ull << nv) - 1ull);
    lv1 = has2 ? ((nv >= 128) ? ~0ull : ((1ull << (nv - 64)) - 1ull)) : 0ull;
    for (;;) {
        int p;
        if (lv0)      p = __builtin_ctzll(lv0);
        else if (lv1) p = 64 + __builtin_ctzll(lv1);
        else          break;
        const int sp = __builtin_amdgcn_readfirstlane(p);

        float px1, py1, px2, py2;
        if (sp < 64) {
            px1 = readlanef(sb0.x, sp); py1 = readlanef(sb0.y, sp);
            px2 = readlanef(sb0.z, sp); py2 = readlanef(sb0.w, sp);
            kb0 |= 1ull << sp;  lv0 &= ~(1ull << sp);
        } else {
            const int sq = sp - 64;
            px1 = readlanef(sb1.x, sq); py1 = readlanef(sb1.y, sq);
            px2 = readlanef(sb1.z, sq); py2 = readlanef(sb1.w, sq);
            kb1 |= 1ull << sq;  lv1 &= ~(1ull << sq);
        }
        const float pa = (px2 - px1) * (py2 - py1);

        {   // candidate 0 vs pivot (exact ref IoU expression order)
            float lx = fmaxf(px1, sb0.x);
            float ly = fmaxf(py1, sb0.y);
            float rx = fminf(px2, sb0.z);
            float ry = fminf(py2, sb0.w);
            float iw = fmaxf(rx - lx, 0.0f);
            float ih = fmaxf(ry - ly, 0.0f);
            float inter = iw * ih;
            float den = pa + sa0 - inter + 1e-12f;
            float iou = inter / den;
            lv0 &= ~__ballot(a0 && (lane > sp) && (iou > NMS_THR_C));
        }
        if (has2) {
            float lx = fmaxf(px1, sb1.x);
            float ly = fmaxf(py1, sb1.y);
            float rx = fminf(px2, sb1.z);
            float ry = fminf(py2, sb1.w);
            float iw = fmaxf(rx - lx, 0.0f);
            float ih = fmaxf(ry - ly, 0.0f);
            float inter = iw * ih;
            float den = pa + sa1 - inter + 1e-12f;
            float iou = inter / den;
            lv1 &= ~__ballot(a1 && (lane + 64 > sp) && (iou > NMS_THR_C));
        }
    }

    // ---- phase 7: kept rows publish into the staged output block ----
    // c==0: one-hot = rank 0 (always kept; ties resolved identically to argmax)
    const bool kept0 = a0 && ((kb0 >> lane) & 1ull) && (c != 0 || lane == 0);
    const bool kept1 = a1 && ((kb1 >> lane) & 1ull) && (c != 0);
    if (kept0) {
        const int base = so0 * 5;
        obuf[base + 0] = fmaxf(sb0.x, 0.0f);
        obuf[base + 1] = fmaxf(sb0.y, 0.0f);
        obuf[base + 2] = fmaxf(sb0.z, 0.0f);
        obuf[base + 3] = fmaxf(sb0.w, 0.0f);
        obuf[base + 4] = fmaxf(sc0,   0.0f);
    }
    if (kept1) {
        const int base = so1 * 5;
        obuf[base + 0] = fmaxf(sb1.x, 0.0f);
        obuf[base + 1] = fmaxf(sb1.y, 0.0f);
        obuf[base + 2] = fmaxf(sb1.z, 0.0f);
        obuf[base + 3] = fmaxf(sb1.w, 0.0f);
        obuf[base + 4] = fmaxf(sc1,   0.0f);
    }

    // ---- phase 8: coalesced float4 copy-out (same-wave LDS ops are ordered) ----
    float* outbc = out + (size_t)bc * 1500;
    #pragma unroll
    for (int k = 0; k < 6; ++k) {
        const int i = lane + 64 * k;
        if (i < 375) {
            const float4 v = ob4[i];
            *reinterpret_cast<float4*>(outbc + 4 * i) = v;
        }
    }
}

extern "C" void kernel_launch(void* const* d_in, const int* in_sizes, int n_in,
                              void* d_out, int out_size, void* d_ws, size_t ws_size,
                              hipStream_t stream) {
    const float* rois   = (const float*)d_in[0];
    const float* pred   = (const float*)d_in[1];
    const float* scores = (const float*)d_in[2];
    const float* iminfo = (const float*)d_in[3];
    float* out = (float*)d_out;
    det_wave6_kernel<<<dim3(1152), dim3(64), 0, stream>>>(rois, pred, scores, iminfo, out);
}

// Round 11
// 18.636 us; speedup vs baseline: 1.0621x; 1.0621x over previous
//
#include <hip/hip_runtime.h>

#define RR 300
#define NCLS 37
#define COUT 36
#define NSTRIP 5
#define CAP2 128           // max candidates (2/lane); nv>64 already ~impossible
#define SCORE_THR_C 0.1f
#define NMS_THR_C 0.4f

__device__ __forceinline__ float readlanef(float x, int sl) {
    return __uint_as_float((unsigned)__builtin_amdgcn_readlane((int)__float_as_uint(x), sl));
}

// One wave per (b,c) pair, one wave per block (1152 blocks -> 4-5 waves/CU,
// evenly spread). Lazy decode: only valid candidates (score>thr) load
// rois/pred and run box decode; non-kept output rows are written as zeros.
// [R11 = verbatim revert to the best-measured kernel (R8, 18.6 us).]
__global__ __launch_bounds__(64) void det_wave4_kernel(
    const float* __restrict__ rois,
    const float* __restrict__ pred,
    const float* __restrict__ scr,
    const float* __restrict__ iminfo,
    float* __restrict__ out)
{
#pragma clang fp contract(off)
    const int bid  = blockIdx.x;
    const int lane = threadIdx.x;                  // 0..63
    // XCD swizzle: 1152 = 8 * 144; XCD k owns batches [4k, 4k+4).
    const int bc   = (bid & 7) * 144 + (bid >> 3);
    const int b    = bc / COUT;
    const int c    = bc % COUT;
    const int cls  = c + 1;

    __shared__ __align__(16) float csc[CAP2 + 4];  // compact scores + pad
    __shared__ int          cro[CAP2];             // compact orig r
    __shared__ float4       sbx[CAP2];             // sorted boxes
    __shared__ int          sor[CAP2];             // sorted orig r
    __shared__ float4       vals4[RR];             // kept rows only: decoded box
    __shared__ unsigned int kpz[80];               // keep flags (320 bytes)

    unsigned char* kp = (unsigned char*)kpz;
    kpz[lane] = 0u;
    if (lane < 16) kpz[64 + lane] = 0u;

    // ---- scores only (the one full-width gather we actually need) ----
    float ss[NSTRIP];
    bool  vv[NSTRIP];
    #pragma unroll
    for (int t = 0; t < NSTRIP; ++t) {
        const int r = lane + 64 * t;
        ss[t] = (r < RR) ? scr[(size_t)(b * RR + r) * NCLS + cls] : 0.f;
        vv[t] = (r < RR) && (ss[t] > SCORE_THR_C);
    }

    // ---- compaction (valid set == prefix of stable argsort(-s)) ----
    const unsigned long long lmask = (1ull << lane) - 1ull;
    int pos[NSTRIP];
    int acc = 0;
    #pragma unroll
    for (int t = 0; t < NSTRIP; ++t) {
        const unsigned long long balt = __ballot(vv[t]);
        pos[t] = acc + __popcll(balt & lmask);
        acc   += __popcll(balt);
    }
    int nv = __builtin_amdgcn_readfirstlane(acc);
    if (nv > CAP2) nv = CAP2;

    #pragma unroll
    for (int t = 0; t < NSTRIP; ++t) {
        if (vv[t] && pos[t] < CAP2) {
            csc[pos[t]] = ss[t];
            cro[pos[t]] = lane + 64 * t;
        }
    }
    if (lane < 4) csc[nv + lane] = -1.0f;          // pad for float4 rank loop

    // ---- lazy gather + decode: candidates only ----
    const float Hm1 = iminfo[b * 3 + 0] - 1.0f;
    const float Wm1 = iminfo[b * 3 + 1] - 1.0f;
    const float scl = iminfo[2];   // im_info[0, 2] for ALL batches (per reference)

    const bool has2 = (nv > 64);
    const bool a0 = (lane < nv);
    const bool a1 = has2 && (lane + 64 < nv);

    float  s0 = -2.f, s1 = -2.f;
    int    o0 = 0, o1 = 0;
    float4 b0 = make_float4(0.f, 0.f, 0.f, 0.f), b1 = b0;
    if (a0) {
        s0 = csc[lane];
        o0 = cro[lane];
        const float4 ro = *reinterpret_cast<const float4*>(rois + (size_t)(b * RR + o0) * 4);
        const float4 pp = *reinterpret_cast<const float4*>(pred + (size_t)(b * RR + o0) * (4 * NCLS) + 4 * cls);
        float w  = ro.z - ro.x + 1.0f;
        float h  = ro.w - ro.y + 1.0f;
        float cx = ro.x + 0.5f * w;
        float cy = ro.y + 0.5f * h;
        float dx = pp.x * 0.1f;
        float dy = pp.y * 0.1f;
        float dw = pp.z * 0.2f;
        float dh = pp.w * 0.2f;
        float pcx = dx * w + cx;
        float pcy = dy * h + cy;
        float pw  = expf(dw) * w;
        float ph  = expf(dh) * h;
        b0.x = fminf(fmaxf(pcx - 0.5f * pw, 0.0f), Wm1) / scl;
        b0.y = fminf(fmaxf(pcy - 0.5f * ph, 0.0f), Hm1) / scl;
        b0.z = fminf(fmaxf(pcx + 0.5f * pw, 0.0f), Wm1) / scl;
        b0.w = fminf(fmaxf(pcy + 0.5f * ph, 0.0f), Hm1) / scl;
    }
    if (a1) {
        s1 = csc[lane + 64];
        o1 = cro[lane + 64];
        const float4 ro = *reinterpret_cast<const float4*>(rois + (size_t)(b * RR + o1) * 4);
        const float4 pp = *reinterpret_cast<const float4*>(pred + (size_t)(b * RR + o1) * (4 * NCLS) + 4 * cls);
        float w  = ro.z - ro.x + 1.0f;
        float h  = ro.w - ro.y + 1.0f;
        float cx = ro.x + 0.5f * w;
        float cy = ro.y + 0.5f * h;
        float dx = pp.x * 0.1f;
        float dy = pp.y * 0.1f;
        float dw = pp.z * 0.2f;
        float dh = pp.w * 0.2f;
        float pcx = dx * w + cx;
        float pcy = dy * h + cy;
        float pw  = expf(dw) * w;
        float ph  = expf(dh) * h;
        b1.x = fminf(fmaxf(pcx - 0.5f * pw, 0.0f), Wm1) / scl;
        b1.y = fminf(fmaxf(pcy - 0.5f * ph, 0.0f), Hm1) / scl;
        b1.z = fminf(fmaxf(pcx + 0.5f * pw, 0.0f), Wm1) / scl;
        b1.w = fminf(fmaxf(pcy + 0.5f * ph, 0.0f), Hm1) / scl;
    }

    // ---- stable descending rank (float4 LDS reads; tie by compact pos) ----
    int r0 = 0, r1 = 0;
    const float4* cs4 = reinterpret_cast<const float4*>(&csc[0]);
    const int n4 = (nv + 3) >> 2;
    for (int q4 = 0; q4 < n4; ++q4) {
        const float4 sv = cs4[q4];
        const int qb = q4 * 4;
        r0 += (int)(sv.x > s0) + ((int)(sv.x == s0) & (int)(qb + 0 < lane));
        r0 += (int)(sv.y > s0) + ((int)(sv.y == s0) & (int)(qb + 1 < lane));
        r0 += (int)(sv.z > s0) + ((int)(sv.z == s0) & (int)(qb + 2 < lane));
        r0 += (int)(sv.w > s0) + ((int)(sv.w == s0) & (int)(qb + 3 < lane));
    }
    if (has2) {
        for (int q4 = 0; q4 < n4; ++q4) {
            const float4 sv = cs4[q4];
            const int qb = q4 * 4, me = lane + 64;
            r1 += (int)(sv.x > s1) + ((int)(sv.x == s1) & (int)(qb + 0 < me));
            r1 += (int)(sv.y > s1) + ((int)(sv.y == s1) & (int)(qb + 1 < me));
            r1 += (int)(sv.z > s1) + ((int)(sv.z == s1) & (int)(qb + 2 < me));
            r1 += (int)(sv.w > s1) + ((int)(sv.w == s1) & (int)(qb + 3 < me));
        }
    }

    // ---- scatter by rank; read back sorted candidate per lane ----
    if (a0) { sbx[r0] = b0; sor[r0] = o0; }
    if (a1) { sbx[r1] = b1; sor[r1] = o1; }
    float4 sb0 = make_float4(0.f, 0.f, 0.f, 0.f), sb1 = sb0;
    float  sa0 = 0.f, sa1 = 0.f;
    int    so0 = 0, so1 = 0;
    if (a0) { sb0 = sbx[lane];      so0 = sor[lane];
              sa0 = (sb0.z - sb0.x) * (sb0.w - sb0.y); }
    if (a1) { sb1 = sbx[lane + 64]; so1 = sor[lane + 64];
              sa1 = (sb1.z - sb1.x) * (sb1.w - sb1.y); }

    // ---- greedy NMS: pivot broadcast via v_readlane (no LDS, no barriers) ----
    unsigned long long lv0, lv1, kb0 = 0ull, kb1 = 0ull;
    lv0 = (nv >= 64) ? ~0ull : ((1ull << nv) - 1ull);
    lv1 = has2 ? ((nv >= 128) ? ~0ull : ((1ull << (nv - 64)) - 1ull)) : 0ull;
    int top_orig = -1;
    for (;;) {
        int p;
        if (lv0)      p = __builtin_ctzll(lv0);
        else if (lv1) p = 64 + __builtin_ctzll(lv1);
        else          break;
        const int sp = __builtin_amdgcn_readfirstlane(p);

        float px1, py1, px2, py2;
        int   po;
        if (sp < 64) {
            px1 = readlanef(sb0.x, sp); py1 = readlanef(sb0.y, sp);
            px2 = readlanef(sb0.z, sp); py2 = readlanef(sb0.w, sp);
            po  = __builtin_amdgcn_readlane(so0, sp);
            kb0 |= 1ull << sp;  lv0 &= ~(1ull << sp);
        } else {
            const int sq = sp - 64;
            px1 = readlanef(sb1.x, sq); py1 = readlanef(sb1.y, sq);
            px2 = readlanef(sb1.z, sq); py2 = readlanef(sb1.w, sq);
            po  = __builtin_amdgcn_readlane(so1, sq);
            kb1 |= 1ull << sq;  lv1 &= ~(1ull << sq);
        }
        if (top_orig < 0) top_orig = po;
        const float pa = (px2 - px1) * (py2 - py1);

        {   // candidate 0 vs pivot (exact ref IoU expression order)
            float lx = fmaxf(px1, sb0.x);
            float ly = fmaxf(py1, sb0.y);
            float rx = fminf(px2, sb0.z);
            float ry = fminf(py2, sb0.w);
            float iw = fmaxf(rx - lx, 0.0f);
            float ih = fmaxf(ry - ly, 0.0f);
            float inter = iw * ih;
            float den = pa + sa0 - inter + 1e-12f;
            float iou = inter / den;
            lv0 &= ~__ballot(a0 && (lane > sp) && (iou > NMS_THR_C));
        }
        if (has2) {
            float lx = fmaxf(px1, sb1.x);
            float ly = fmaxf(py1, sb1.y);
            float rx = fminf(px2, sb1.z);
            float ry = fminf(py2, sb1.w);
            float iw = fmaxf(rx - lx, 0.0f);
            float ih = fmaxf(ry - ly, 0.0f);
            float inter = iw * ih;
            float den = pa + sa1 - inter + 1e-12f;
            float iou = inter / den;
            lv1 &= ~__ballot(a1 && (lane + 64 > sp) && (iou > NMS_THR_C));
        }
    }

    // ---- kept rows publish their decoded box (by orig r) ----
    if (a0 && ((kb0 >> lane) & 1ull)) { vals4[so0] = sb0; kp[so0] = 1; }
    if (a1 && ((kb1 >> lane) & 1ull)) { vals4[so1] = sb1; kp[so1] = 1; }

    // ---- write: zeros for non-kept rows, box+score for kept ----
    #pragma unroll
    for (int t = 0; t < NSTRIP; ++t) {
        const int r = lane + 64 * t;
        if (r < RR) {
            const bool k = (c == 0) ? (r == top_orig) : (kp[r] != 0);
            float q0 = 0.f, q1 = 0.f, q2 = 0.f, q3 = 0.f, q4 = 0.f;
            if (k) {
                const float4 v4 = vals4[r];
                q0 = fmaxf(v4.x, 0.0f);
                q1 = fmaxf(v4.y, 0.0f);
                q2 = fmaxf(v4.z, 0.0f);
                q3 = fmaxf(v4.w, 0.0f);
                q4 = fmaxf(ss[t], 0.0f);
            }
            const size_t base = (((size_t)b * COUT + c) * RR + r) * 5;
            out[base + 0] = q0;
            out[base + 1] = q1;
            out[base + 2] = q2;
            out[base + 3] = q3;
            out[base + 4] = q4;
        }
    }
}

extern "C" void kernel_launch(void* const* d_in, const int* in_sizes, int n_in,
                              void* d_out, int out_size, void* d_ws, size_t ws_size,
                              hipStream_t stream) {
    const float* rois   = (const float*)d_in[0];
    const float* pred   = (const float*)d_in[1];
    const float* scores = (const float*)d_in[2];
    const float* iminfo = (const float*)d_in[3];
    float* out = (float*)d_out;
    det_wave4_kernel<<<dim3(1152), dim3(64), 0, stream>>>(rois, pred, scores, iminfo, out);
}